// Round 1
// baseline (993.960 us; speedup 1.0000x reference)
//
#include <hip/hip_runtime.h>
#include <math.h>

#define SCAN_B 512

// ---------------- degree count ----------------
__global__ void count_deg_kernel(const int* __restrict__ dst, int E, int* __restrict__ counts) {
    int e = blockIdx.x * blockDim.x + threadIdx.x;
    if (e < E) atomicAdd(&counts[dst[e]], 1);
}

// ---------------- exclusive scan (3-phase) ----------------
__global__ void scan1_kernel(const int* __restrict__ counts, int N,
                             int* __restrict__ partial, int* __restrict__ blockSums) {
    __shared__ int sm[SCAN_B];
    int tid = threadIdx.x;
    int i = blockIdx.x * SCAN_B + tid;
    int v = (i < N) ? counts[i] : 0;
    sm[tid] = v;
    __syncthreads();
    for (int off = 1; off < SCAN_B; off <<= 1) {
        int t = (tid >= off) ? sm[tid - off] : 0;
        __syncthreads();
        sm[tid] += t;
        __syncthreads();
    }
    if (i < N) partial[i] = sm[tid] - v;  // exclusive
    if (tid == SCAN_B - 1) blockSums[blockIdx.x] = sm[tid];
}

__global__ void scan2_kernel(int* __restrict__ blockSums, int nb) {
    __shared__ int sm[256];
    int tid = threadIdx.x;
    int v = (tid < nb) ? blockSums[tid] : 0;
    sm[tid] = v;
    __syncthreads();
    for (int off = 1; off < 256; off <<= 1) {
        int t = (tid >= off) ? sm[tid - off] : 0;
        __syncthreads();
        sm[tid] += t;
        __syncthreads();
    }
    if (tid < nb) blockSums[tid] = sm[tid] - v;  // exclusive
}

__global__ void scan3_kernel(const int* __restrict__ counts, int* __restrict__ offsets,
                             const int* __restrict__ blockSums, int N, int E,
                             int* __restrict__ cursor, float* __restrict__ dinv) {
    int i = blockIdx.x * SCAN_B + threadIdx.x;
    if (i < N) {
        int off = offsets[i] + blockSums[blockIdx.x];
        offsets[i] = off;
        cursor[i] = off;
        // deg includes the self-loop: counts (in-degree) + 1, so deg >= 1 always
        dinv[i] = rsqrtf((float)(counts[i] + 1));
    }
    if (i == 0 && blockIdx.x == 0) offsets[N] = E;
}

// ---------------- CSR scatter ----------------
__global__ void scatter_kernel(const int* __restrict__ src, const int* __restrict__ dst, int E,
                               int* __restrict__ cursor, int* __restrict__ ssrc) {
    int e = blockIdx.x * blockDim.x + threadIdx.x;
    if (e < E) {
        int p = atomicAdd(&cursor[dst[e]], 1);
        ssrc[p] = src[e];
    }
}

// ---------------- GEMM1: [N,512] @ [512,128] -> [N,128], f32 ----------------
__global__ __launch_bounds__(256) void gemm1_kernel(const float* __restrict__ X,
                                                    const float* __restrict__ W,
                                                    float* __restrict__ H, int N) {
    __shared__ float As[32][64];    // A tile transposed: [k][m], 8 KB
    __shared__ float Bs[32][128];   // B tile: [k][n], 16 KB
    int tid = threadIdx.x;
    int tx = tid & 15;   // col group: cols tx*8 .. +7
    int ty = tid >> 4;   // row group: rows ty*4 .. +3
    int rowBase = blockIdx.x * 64;

    float acc[4][8];
    #pragma unroll
    for (int r = 0; r < 4; r++)
        #pragma unroll
        for (int c = 0; c < 8; c++) acc[r][c] = 0.f;

    for (int k0 = 0; k0 < 512; k0 += 32) {
        // load A tile: 64 rows x 32 k = 512 float4, 2 per thread
        #pragma unroll
        for (int l = 0; l < 2; l++) {
            int e = tid + l * 256;
            int r = e >> 3;            // 8 float4 per row
            int kk = (e & 7) << 2;
            int grow = rowBase + r;
            float4 v = make_float4(0.f, 0.f, 0.f, 0.f);
            if (grow < N) v = *(const float4*)&X[grow * 512 + k0 + kk];
            As[kk + 0][r] = v.x; As[kk + 1][r] = v.y;
            As[kk + 2][r] = v.z; As[kk + 3][r] = v.w;
        }
        // load B tile: 32 k x 128 n = 1024 float4, 4 per thread
        #pragma unroll
        for (int l = 0; l < 4; l++) {
            int e = tid + l * 256;
            int kk = e >> 5;           // 32 float4 per k-row
            int nn = (e & 31) << 2;
            *(float4*)&Bs[kk][nn] = *(const float4*)&W[(k0 + kk) * 128 + nn];
        }
        __syncthreads();
        #pragma unroll
        for (int k = 0; k < 32; k++) {
            float4 a = *(float4*)&As[k][ty * 4];
            float4 b0 = *(float4*)&Bs[k][tx * 8];
            float4 b1 = *(float4*)&Bs[k][tx * 8 + 4];
            float av[4] = {a.x, a.y, a.z, a.w};
            float bv[8] = {b0.x, b0.y, b0.z, b0.w, b1.x, b1.y, b1.z, b1.w};
            #pragma unroll
            for (int r = 0; r < 4; r++)
                #pragma unroll
                for (int c = 0; c < 8; c++)
                    acc[r][c] = fmaf(av[r], bv[c], acc[r][c]);
        }
        __syncthreads();
    }
    #pragma unroll
    for (int r = 0; r < 4; r++) {
        int grow = rowBase + ty * 4 + r;
        if (grow < N) {
            *(float4*)&H[grow * 128 + tx * 8] =
                make_float4(acc[r][0], acc[r][1], acc[r][2], acc[r][3]);
            *(float4*)&H[grow * 128 + tx * 8 + 4] =
                make_float4(acc[r][4], acc[r][5], acc[r][6], acc[r][7]);
        }
    }
}

// ---------------- Agg1: out[i] = dinv[i]*(dinv[i]*h[i] + sum dinv[s]*h[s]) + b; relu ----------------
__global__ __launch_bounds__(128) void agg1_kernel(const float* __restrict__ h1,
                                                   const int* __restrict__ offsets,
                                                   const int* __restrict__ ssrc,
                                                   const float* __restrict__ dinv,
                                                   const float* __restrict__ bias,
                                                   float* __restrict__ a1, int N) {
    int i = blockIdx.x;
    int t = threadIdx.x;  // column 0..127
    float di = dinv[i];
    float acc = di * h1[(size_t)i * 128 + t];  // self loop (norm = di*di, outer di applied below)
    int s0 = offsets[i], s1 = offsets[i + 1];
    for (int e = s0; e < s1; e++) {
        int s = ssrc[e];
        float w = dinv[s];
        acc = fmaf(w, h1[(size_t)s * 128 + t], acc);
    }
    float v = fmaf(di, acc, bias[t]);
    a1[(size_t)i * 128 + t] = fmaxf(v, 0.f);
}

// ---------------- GEMM2: [N,128] @ [128,40] -> [N,40], f32, W fully in LDS ----------------
__global__ __launch_bounds__(256) void gemm2_kernel(const float* __restrict__ A,
                                                    const float* __restrict__ W,
                                                    float* __restrict__ H, int N) {
    __shared__ float As[128][64];    // 32 KB, [k][m]
    __shared__ float Ws[128 * 40];   // 20 KB
    int tid = threadIdx.x;
    int rowBase = blockIdx.x * 64;

    // load A tile: 64 rows x 128 k = 2048 float4, 8 per thread
    #pragma unroll
    for (int l = 0; l < 8; l++) {
        int e = tid + l * 256;
        int r = e >> 5;           // 32 float4 per row
        int kk = (e & 31) << 2;
        int grow = rowBase + r;
        float4 v = make_float4(0.f, 0.f, 0.f, 0.f);
        if (grow < N) v = *(const float4*)&A[grow * 128 + kk];
        As[kk + 0][r] = v.x; As[kk + 1][r] = v.y;
        As[kk + 2][r] = v.z; As[kk + 3][r] = v.w;
    }
    // load whole W: 5120 floats = 1280 float4, 5 per thread
    #pragma unroll
    for (int l = 0; l < 5; l++) {
        int e = tid + l * 256;
        *(float4*)&Ws[e << 2] = *(const float4*)&W[e << 2];
    }
    __syncthreads();

    int tx = tid & 7;    // col group: cols tx*5 .. +4
    int ty = tid >> 3;   // 0..31: rows ty*2, ty*2+1
    float acc[2][5];
    #pragma unroll
    for (int r = 0; r < 2; r++)
        #pragma unroll
        for (int c = 0; c < 5; c++) acc[r][c] = 0.f;

    #pragma unroll 8
    for (int k = 0; k < 128; k++) {
        float a0 = As[k][ty * 2];
        float a1v = As[k][ty * 2 + 1];
        #pragma unroll
        for (int c = 0; c < 5; c++) {
            float w = Ws[k * 40 + tx * 5 + c];
            acc[0][c] = fmaf(a0, w, acc[0][c]);
            acc[1][c] = fmaf(a1v, w, acc[1][c]);
        }
    }
    #pragma unroll
    for (int r = 0; r < 2; r++) {
        int grow = rowBase + ty * 2 + r;
        if (grow < N) {
            #pragma unroll
            for (int c = 0; c < 5; c++) H[grow * 40 + tx * 5 + c] = acc[r][c];
        }
    }
}

// ---------------- Agg2 + bias + log_softmax (wave per node) ----------------
__global__ __launch_bounds__(256) void agg2_kernel(const float* __restrict__ h2,
                                                   const int* __restrict__ offsets,
                                                   const int* __restrict__ ssrc,
                                                   const float* __restrict__ dinv,
                                                   const float* __restrict__ bias,
                                                   float* __restrict__ out, int N) {
    int node = blockIdx.x * 4 + (threadIdx.x >> 6);
    int lane = threadIdx.x & 63;
    if (node >= N) return;
    float di = dinv[node];
    float acc = 0.f;
    if (lane < 40) acc = di * h2[(size_t)node * 40 + lane];
    int s0 = offsets[node], s1 = offsets[node + 1];
    for (int e = s0; e < s1; e++) {
        int s = ssrc[e];
        float w = dinv[s];
        if (lane < 40) acc = fmaf(w, h2[(size_t)s * 40 + lane], acc);
    }
    float v = (lane < 40) ? fmaf(di, acc, bias[lane]) : -INFINITY;
    // wave max
    float m = v;
    #pragma unroll
    for (int off = 32; off; off >>= 1) m = fmaxf(m, __shfl_xor(m, off, 64));
    float ex = (lane < 40) ? expf(v - m) : 0.f;
    float s = ex;
    #pragma unroll
    for (int off = 32; off; off >>= 1) s += __shfl_xor(s, off, 64);
    if (lane < 40) out[(size_t)node * 40 + lane] = v - m - logf(s);
}

// ---------------- launch ----------------
extern "C" void kernel_launch(void* const* d_in, const int* in_sizes, int n_in,
                              void* d_out, int out_size, void* d_ws, size_t ws_size,
                              hipStream_t stream) {
    const float* x  = (const float*)d_in[0];
    const int*   ei = (const int*)d_in[1];
    const float* W1 = (const float*)d_in[2];
    const float* b1 = (const float*)d_in[3];
    const float* W2 = (const float*)d_in[4];
    const float* b2 = (const float*)d_in[5];
    float* out = (float*)d_out;

    int N = in_sizes[0] / 512;
    int E = in_sizes[1] / 2;
    const int* src = ei;
    const int* dst = ei + E;

    char* ws = (char*)d_ws;
    size_t off = 0;
    auto alloc = [&](size_t bytes) -> void* {
        void* p = ws + off;
        off += (bytes + 255) & ~(size_t)255;
        return p;
    };
    int*   counts    = (int*)alloc((size_t)N * 4);
    int*   offsets   = (int*)alloc((size_t)(N + 1) * 4);
    int*   cursor    = (int*)alloc((size_t)N * 4);
    float* dinv      = (float*)alloc((size_t)N * 4);
    int nb = (N + SCAN_B - 1) / SCAN_B;
    int*   blockSums = (int*)alloc((size_t)nb * 4);
    int*   ssrc      = (int*)alloc((size_t)E * 4);
    float* h1        = (float*)alloc((size_t)N * 128 * 4);
    float* a1        = (float*)alloc((size_t)N * 128 * 4);
    float* h2        = (float*)alloc((size_t)N * 40 * 4);
    (void)ws_size; (void)n_in; (void)out_size;

    hipMemsetAsync(counts, 0, (size_t)N * 4, stream);
    count_deg_kernel<<<(E + 255) / 256, 256, 0, stream>>>(dst, E, counts);
    scan1_kernel<<<nb, SCAN_B, 0, stream>>>(counts, N, offsets, blockSums);
    scan2_kernel<<<1, 256, 0, stream>>>(blockSums, nb);
    scan3_kernel<<<nb, SCAN_B, 0, stream>>>(counts, offsets, blockSums, N, E, cursor, dinv);
    scatter_kernel<<<(E + 255) / 256, 256, 0, stream>>>(src, dst, E, cursor, ssrc);
    gemm1_kernel<<<(N + 63) / 64, 256, 0, stream>>>(x, W1, h1, N);
    agg1_kernel<<<N, 128, 0, stream>>>(h1, offsets, ssrc, dinv, b1, a1, N);
    gemm2_kernel<<<(N + 63) / 64, 256, 0, stream>>>(a1, W2, h2, N);
    agg2_kernel<<<(N + 3) / 4, 256, 0, stream>>>(h2, offsets, ssrc, dinv, b2, out, N);
}

// Round 3
// 804.647 us; speedup vs baseline: 1.2353x; 1.2353x over previous
//
#include <hip/hip_runtime.h>
#include <math.h>

#define SCAN_B 512

typedef __attribute__((ext_vector_type(8))) short short8;
typedef __attribute__((ext_vector_type(4))) float v4f;

__device__ __forceinline__ unsigned short f2bf(float f) {
    unsigned int u = __float_as_uint(f);
    u += 0x7FFFu + ((u >> 16) & 1u);  // round-to-nearest-even
    return (unsigned short)(u >> 16);
}

// ---------------- degree count ----------------
__global__ void count_deg_kernel(const int* __restrict__ dst, int E, int* __restrict__ counts) {
    int e = blockIdx.x * blockDim.x + threadIdx.x;
    if (e < E) atomicAdd(&counts[dst[e]], 1);
}

// ---------------- exclusive scan (3-phase) ----------------
__global__ void scan1_kernel(const int* __restrict__ counts, int N,
                             int* __restrict__ partial, int* __restrict__ blockSums) {
    __shared__ int sm[SCAN_B];
    int tid = threadIdx.x;
    int i = blockIdx.x * SCAN_B + tid;
    int v = (i < N) ? counts[i] : 0;
    sm[tid] = v;
    __syncthreads();
    for (int off = 1; off < SCAN_B; off <<= 1) {
        int t = (tid >= off) ? sm[tid - off] : 0;
        __syncthreads();
        sm[tid] += t;
        __syncthreads();
    }
    if (i < N) partial[i] = sm[tid] - v;  // exclusive
    if (tid == SCAN_B - 1) blockSums[blockIdx.x] = sm[tid];
}

__global__ void scan2_kernel(int* __restrict__ blockSums, int nb) {
    __shared__ int sm[256];
    int tid = threadIdx.x;
    int v = (tid < nb) ? blockSums[tid] : 0;
    sm[tid] = v;
    __syncthreads();
    for (int off = 1; off < 256; off <<= 1) {
        int t = (tid >= off) ? sm[tid - off] : 0;
        __syncthreads();
        sm[tid] += t;
        __syncthreads();
    }
    if (tid < nb) blockSums[tid] = sm[tid] - v;  // exclusive
}

__global__ void scan3_kernel(const int* __restrict__ counts, int* __restrict__ offsets,
                             const int* __restrict__ blockSums, int N, int E,
                             int* __restrict__ cursor, float* __restrict__ dinv) {
    int i = blockIdx.x * SCAN_B + threadIdx.x;
    if (i < N) {
        int off = offsets[i] + blockSums[blockIdx.x];
        offsets[i] = off;
        cursor[i] = off;
        dinv[i] = rsqrtf((float)(counts[i] + 1));  // deg includes self-loop
    }
    if (i == 0 && blockIdx.x == 0) offsets[N] = E;
}

// ---------------- CSR scatter ----------------
__global__ void scatter_kernel(const int* __restrict__ src, const int* __restrict__ dst, int E,
                               int* __restrict__ cursor, int* __restrict__ ssrc) {
    int e = blockIdx.x * blockDim.x + threadIdx.x;
    if (e < E) {
        int p = atomicAdd(&cursor[dst[e]], 1);
        ssrc[p] = src[e];
    }
}

// ---------------- W1 transpose + cast: [512,128] f32 -> [128,512] bf16 ----------------
__global__ void w1cast_kernel(const float* __restrict__ W1, unsigned short* __restrict__ W1t) {
    int idx = blockIdx.x * 256 + threadIdx.x;  // 65536 total
    int k = idx >> 7, n = idx & 127;
    W1t[n * 512 + k] = f2bf(W1[idx]);
}

// ---------------- GEMM1: [N,512] @ [512,128] -> [N,128], bf16 MFMA ----------------
#define BM 128
#define BN 128
#define BK 64
#define LDT 72  // padded LDS row (bf16 elems), 144 B = 9*16B

__global__ __launch_bounds__(256) void gemm1_mfma_kernel(const float* __restrict__ X,
                                                         const unsigned short* __restrict__ W1t,
                                                         float* __restrict__ H, int N) {
    __shared__ unsigned short As[BM * LDT];  // 18 KB, A[m][k] k-contiguous
    __shared__ unsigned short Bs[BN * LDT];  // 18 KB, B[n][k] k-contiguous
    int tid = threadIdx.x;
    int wave = tid >> 6, lane = tid & 63;
    int quad = lane >> 4, lr = lane & 15;
    int mBase = (wave & 1) * 64, nBase = (wave >> 1) * 64;
    int rowBase = blockIdx.x * BM;

    v4f zero = {0.f, 0.f, 0.f, 0.f};
    v4f acc[4][4];
    #pragma unroll
    for (int i = 0; i < 4; i++)
        #pragma unroll
        for (int j = 0; j < 4; j++) acc[i][j] = zero;

    for (int k0 = 0; k0 < 512; k0 += BK) {
        // A staging: 128 rows x 64 k f32 -> bf16. 2048 float4, 8/thread.
        #pragma unroll
        for (int t = 0; t < 8; t++) {
            int idx = tid + t * 256;
            int r = idx >> 4;             // 16 float4 per row
            int kk = (idx & 15) << 2;
            float4 v = make_float4(0.f, 0.f, 0.f, 0.f);
            int gr = rowBase + r;
            if (gr < N) v = *(const float4*)(X + (size_t)gr * 512 + k0 + kk);
            ushort4 b;
            b.x = f2bf(v.x); b.y = f2bf(v.y); b.z = f2bf(v.z); b.w = f2bf(v.w);
            *(ushort4*)(&As[r * LDT + kk]) = b;
        }
        // B staging: 128 n x 64 k bf16 = 16 KB = 1024 x 16B chunks, 4/thread.
        #pragma unroll
        for (int t = 0; t < 4; t++) {
            int idx = tid + t * 256;      // 0..1023
            int n = idx >> 3;             // 0..127 (8 x 16B per row)
            int kk = (idx & 7) << 3;
            uint4 v = *(const uint4*)(W1t + (size_t)n * 512 + k0 + kk);
            *(uint4*)(&Bs[n * LDT + kk]) = v;
        }
        __syncthreads();
        #pragma unroll
        for (int kc = 0; kc < BK; kc += 32) {
            short8 aF[4], bF[4];
            #pragma unroll
            for (int i = 0; i < 4; i++) {
                aF[i] = *(const short8*)(&As[(mBase + i * 16 + lr) * LDT + kc + quad * 8]);
                bF[i] = *(const short8*)(&Bs[(nBase + i * 16 + lr) * LDT + kc + quad * 8]);
            }
            #pragma unroll
            for (int i = 0; i < 4; i++)
                #pragma unroll
                for (int j = 0; j < 4; j++)
                    acc[i][j] = __builtin_amdgcn_mfma_f32_16x16x32_bf16(aF[i], bF[j], acc[i][j], 0, 0, 0);
        }
        __syncthreads();
    }
    // epilogue: C/D layout col=lane&15, row=quad*4+reg
    #pragma unroll
    for (int i = 0; i < 4; i++) {
        #pragma unroll
        for (int r = 0; r < 4; r++) {
            int m = rowBase + mBase + i * 16 + quad * 4 + r;
            if (m < N) {
                #pragma unroll
                for (int j = 0; j < 4; j++)
                    H[(size_t)m * 128 + nBase + j * 16 + lr] = acc[i][j][r];
            }
        }
    }
}

// ---------------- Agg1: 32 threads/node, float4/lane, unroll 2 ----------------
__global__ __launch_bounds__(256) void agg1_kernel(const float* __restrict__ h1,
                                                   const int* __restrict__ offsets,
                                                   const int* __restrict__ ssrc,
                                                   const float* __restrict__ dinv,
                                                   const float* __restrict__ bias,
                                                   float* __restrict__ a1, int N) {
    int lane = threadIdx.x & 31;
    int node = (blockIdx.x << 3) + (threadIdx.x >> 5);
    if (node >= N) return;
    float di = dinv[node];
    const float4* h = (const float4*)h1;
    float4 v = h[(size_t)node * 32 + lane];
    float4 acc;
    acc.x = di * v.x; acc.y = di * v.y; acc.z = di * v.z; acc.w = di * v.w;
    int e = offsets[node], e1 = offsets[node + 1];
    for (; e + 1 < e1; e += 2) {
        int sA = ssrc[e], sB = ssrc[e + 1];
        float wA = dinv[sA], wB = dinv[sB];
        float4 hA = h[(size_t)sA * 32 + lane];
        float4 hB = h[(size_t)sB * 32 + lane];
        acc.x = fmaf(wA, hA.x, acc.x); acc.y = fmaf(wA, hA.y, acc.y);
        acc.z = fmaf(wA, hA.z, acc.z); acc.w = fmaf(wA, hA.w, acc.w);
        acc.x = fmaf(wB, hB.x, acc.x); acc.y = fmaf(wB, hB.y, acc.y);
        acc.z = fmaf(wB, hB.z, acc.z); acc.w = fmaf(wB, hB.w, acc.w);
    }
    if (e < e1) {
        int s = ssrc[e];
        float w = dinv[s];
        float4 hs = h[(size_t)s * 32 + lane];
        acc.x = fmaf(w, hs.x, acc.x); acc.y = fmaf(w, hs.y, acc.y);
        acc.z = fmaf(w, hs.z, acc.z); acc.w = fmaf(w, hs.w, acc.w);
    }
    float4 b = ((const float4*)bias)[lane];
    float4 o;
    o.x = fmaxf(fmaf(di, acc.x, b.x), 0.f);
    o.y = fmaxf(fmaf(di, acc.y, b.y), 0.f);
    o.z = fmaxf(fmaf(di, acc.z, b.z), 0.f);
    o.w = fmaxf(fmaf(di, acc.w, b.w), 0.f);
    ((float4*)a1)[(size_t)node * 32 + lane] = o;
}

// ---------------- GEMM2: [N,128] @ [128,40] -> [N,40], f32, W fully in LDS ----------------
__global__ __launch_bounds__(256) void gemm2_kernel(const float* __restrict__ A,
                                                    const float* __restrict__ W,
                                                    float* __restrict__ H, int N) {
    __shared__ float As2[128][64];   // 32 KB, [k][m]
    __shared__ float Ws[128 * 40];   // 20 KB
    int tid = threadIdx.x;
    int rowBase = blockIdx.x * 64;

    #pragma unroll
    for (int l = 0; l < 8; l++) {
        int e = tid + l * 256;
        int r = e >> 5;
        int kk = (e & 31) << 2;
        int grow = rowBase + r;
        float4 v = make_float4(0.f, 0.f, 0.f, 0.f);
        if (grow < N) v = *(const float4*)&A[grow * 128 + kk];
        As2[kk + 0][r] = v.x; As2[kk + 1][r] = v.y;
        As2[kk + 2][r] = v.z; As2[kk + 3][r] = v.w;
    }
    #pragma unroll
    for (int l = 0; l < 5; l++) {
        int e = tid + l * 256;
        *(float4*)&Ws[e << 2] = *(const float4*)&W[e << 2];
    }
    __syncthreads();

    int tx = tid & 7;
    int ty = tid >> 3;
    float acc[2][5];
    #pragma unroll
    for (int r = 0; r < 2; r++)
        #pragma unroll
        for (int c = 0; c < 5; c++) acc[r][c] = 0.f;

    #pragma unroll 8
    for (int k = 0; k < 128; k++) {
        float a0 = As2[k][ty * 2];
        float a1v = As2[k][ty * 2 + 1];
        #pragma unroll
        for (int c = 0; c < 5; c++) {
            float w = Ws[k * 40 + tx * 5 + c];
            acc[0][c] = fmaf(a0, w, acc[0][c]);
            acc[1][c] = fmaf(a1v, w, acc[1][c]);
        }
    }
    #pragma unroll
    for (int r = 0; r < 2; r++) {
        int grow = rowBase + ty * 2 + r;
        if (grow < N) {
            #pragma unroll
            for (int c = 0; c < 5; c++) H[grow * 40 + tx * 5 + c] = acc[r][c];
        }
    }
}

// ---------------- Agg2 + bias + log_softmax (wave per node, unroll 4) ----------------
__global__ __launch_bounds__(256) void agg2_kernel(const float* __restrict__ h2,
                                                   const int* __restrict__ offsets,
                                                   const int* __restrict__ ssrc,
                                                   const float* __restrict__ dinv,
                                                   const float* __restrict__ bias,
                                                   float* __restrict__ out, int N) {
    int node = blockIdx.x * 4 + (threadIdx.x >> 6);
    int lane = threadIdx.x & 63;
    if (node >= N) return;
    float di = dinv[node];
    bool act = lane < 40;
    float acc = 0.f;
    if (act) acc = di * h2[(size_t)node * 40 + lane];
    int e = offsets[node], e1 = offsets[node + 1];
    for (; e + 3 < e1; e += 4) {
        int sa = ssrc[e], sb = ssrc[e + 1], sc = ssrc[e + 2], sd = ssrc[e + 3];
        float wa = dinv[sa], wb = dinv[sb], wc = dinv[sc], wd = dinv[sd];
        if (act) {
            float ha = h2[(size_t)sa * 40 + lane];
            float hb = h2[(size_t)sb * 40 + lane];
            float hc = h2[(size_t)sc * 40 + lane];
            float hd = h2[(size_t)sd * 40 + lane];
            acc = fmaf(wa, ha, acc); acc = fmaf(wb, hb, acc);
            acc = fmaf(wc, hc, acc); acc = fmaf(wd, hd, acc);
        }
    }
    for (; e < e1; e++) {
        int s = ssrc[e];
        float w = dinv[s];
        if (act) acc = fmaf(w, h2[(size_t)s * 40 + lane], acc);
    }
    float v = act ? fmaf(di, acc, bias[lane]) : -INFINITY;
    float m = v;
    #pragma unroll
    for (int off = 32; off; off >>= 1) m = fmaxf(m, __shfl_xor(m, off, 64));
    float ex = act ? expf(v - m) : 0.f;
    float s = ex;
    #pragma unroll
    for (int off = 32; off; off >>= 1) s += __shfl_xor(s, off, 64);
    if (act) out[(size_t)node * 40 + lane] = v - m - logf(s);
}

// ---------------- launch ----------------
extern "C" void kernel_launch(void* const* d_in, const int* in_sizes, int n_in,
                              void* d_out, int out_size, void* d_ws, size_t ws_size,
                              hipStream_t stream) {
    const float* x  = (const float*)d_in[0];
    const int*   ei = (const int*)d_in[1];
    const float* W1 = (const float*)d_in[2];
    const float* b1 = (const float*)d_in[3];
    const float* W2 = (const float*)d_in[4];
    const float* b2 = (const float*)d_in[5];
    float* out = (float*)d_out;

    int N = in_sizes[0] / 512;
    int E = in_sizes[1] / 2;
    const int* src = ei;
    const int* dst = ei + E;

    char* ws = (char*)d_ws;
    size_t off = 0;
    auto alloc = [&](size_t bytes) -> void* {
        void* p = ws + off;
        off += (bytes + 255) & ~(size_t)255;
        return p;
    };
    int*   counts    = (int*)alloc((size_t)N * 4);
    int*   offsets   = (int*)alloc((size_t)(N + 1) * 4);
    int*   cursor    = (int*)alloc((size_t)N * 4);
    float* dinv      = (float*)alloc((size_t)N * 4);
    int nb = (N + SCAN_B - 1) / SCAN_B;
    int*   blockSums = (int*)alloc((size_t)nb * 4);
    int*   ssrc      = (int*)alloc((size_t)E * 4);
    unsigned short* W1t = (unsigned short*)alloc((size_t)128 * 512 * 2);
    float* h1        = (float*)alloc((size_t)N * 128 * 4);
    float* a1        = (float*)alloc((size_t)N * 128 * 4);
    float* h2        = (float*)alloc((size_t)N * 40 * 4);
    (void)ws_size; (void)n_in; (void)out_size;

    hipMemsetAsync(counts, 0, (size_t)N * 4, stream);
    count_deg_kernel<<<(E + 255) / 256, 256, 0, stream>>>(dst, E, counts);
    scan1_kernel<<<nb, SCAN_B, 0, stream>>>(counts, N, offsets, blockSums);
    scan2_kernel<<<1, 256, 0, stream>>>(blockSums, nb);
    scan3_kernel<<<nb, SCAN_B, 0, stream>>>(counts, offsets, blockSums, N, E, cursor, dinv);
    scatter_kernel<<<(E + 255) / 256, 256, 0, stream>>>(src, dst, E, cursor, ssrc);
    w1cast_kernel<<<256, 256, 0, stream>>>(W1, W1t);
    gemm1_mfma_kernel<<<(N + BM - 1) / BM, 256, 0, stream>>>(x, W1t, h1, N);
    agg1_kernel<<<(N + 7) / 8, 256, 0, stream>>>(h1, offsets, ssrc, dinv, b1, a1, N);
    gemm2_kernel<<<(N + 63) / 64, 256, 0, stream>>>(a1, W2, h2, N);
    agg2_kernel<<<(N + 3) / 4, 256, 0, stream>>>(h2, offsets, ssrc, dinv, b2, out, N);
}

// Round 4
// 735.010 us; speedup vs baseline: 1.3523x; 1.0947x over previous
//
#include <hip/hip_runtime.h>
#include <math.h>

#define SCAN_B 512
#define NBSHIFT 8
#define CHUNK 8192

typedef __attribute__((ext_vector_type(8))) short short8;
typedef __attribute__((ext_vector_type(4))) float v4f;

__device__ __forceinline__ unsigned short f2bf(float f) {
    unsigned int u = __float_as_uint(f);
    u += 0x7FFFu + ((u >> 16) & 1u);  // RNE
    return (unsigned short)(u >> 16);
}

// ---------------- degree count ----------------
__global__ void count_deg_kernel(const int* __restrict__ dst, int E, int* __restrict__ counts) {
    int e = blockIdx.x * blockDim.x + threadIdx.x;
    if (e < E) atomicAdd(&counts[dst[e]], 1);
}

// ---------------- exclusive scan (3-phase) ----------------
__global__ void scan1_kernel(const int* __restrict__ counts, int N,
                             int* __restrict__ partial, int* __restrict__ blockSums) {
    __shared__ int sm[SCAN_B];
    int tid = threadIdx.x;
    int i = blockIdx.x * SCAN_B + tid;
    int v = (i < N) ? counts[i] : 0;
    sm[tid] = v;
    __syncthreads();
    for (int off = 1; off < SCAN_B; off <<= 1) {
        int t = (tid >= off) ? sm[tid - off] : 0;
        __syncthreads();
        sm[tid] += t;
        __syncthreads();
    }
    if (i < N) partial[i] = sm[tid] - v;
    if (tid == SCAN_B - 1) blockSums[blockIdx.x] = sm[tid];
}

__global__ void scan2_kernel(int* __restrict__ blockSums, int nb) {
    __shared__ int sm[256];
    int tid = threadIdx.x;
    int v = (tid < nb) ? blockSums[tid] : 0;
    sm[tid] = v;
    __syncthreads();
    for (int off = 1; off < 256; off <<= 1) {
        int t = (tid >= off) ? sm[tid - off] : 0;
        __syncthreads();
        sm[tid] += t;
        __syncthreads();
    }
    if (tid < nb) blockSums[tid] = sm[tid] - v;
}

__global__ void scan3_kernel(const int* __restrict__ counts, int* __restrict__ offsets,
                             const int* __restrict__ blockSums, int N, int E,
                             int* __restrict__ cursor, float* __restrict__ dinv) {
    int i = blockIdx.x * SCAN_B + threadIdx.x;
    if (i < N) {
        int off = offsets[i] + blockSums[blockIdx.x];
        offsets[i] = off;
        cursor[i] = off;
        dinv[i] = rsqrtf((float)(counts[i] + 1));
    }
    if (i == 0 && blockIdx.x == 0) offsets[N] = E;
}

// ---------------- bin bases: bin_base[b] = offsets[min(b<<8,N)], cursor init ----------------
__global__ void binbase_kernel(const int* __restrict__ offsets, int* __restrict__ bin_base,
                               int* __restrict__ bin_cursor, int nbins, int N) {
    int b = blockIdx.x * 256 + threadIdx.x;
    if (b <= nbins) {
        int node = b << NBSHIFT;
        if (node > N) node = N;
        bin_base[b] = offsets[node];
        if (b < nbins) bin_cursor[b] = offsets[node];
    }
}

// ---------------- phase B: local counting-sort into coarse bins ----------------
__global__ __launch_bounds__(256) void binpass_kernel(const int* __restrict__ src,
                                                      const int* __restrict__ dst, int E,
                                                      int* __restrict__ bin_cursor,
                                                      unsigned int* __restrict__ bpairs, int nbins) {
    __shared__ unsigned int pk[CHUNK];        // 32 KB packed edges
    __shared__ unsigned short binOf[CHUNK];   // 16 KB
    __shared__ int hist[512];
    __shared__ int scanned[512];
    __shared__ int rank[512];
    __shared__ int gbase[512];
    int tid = threadIdx.x;
    int base = blockIdx.x * CHUNK;
    int cnt = E - base; if (cnt > CHUNK) cnt = CHUNK;

    for (int i = tid; i < 512; i += 256) { hist[i] = 0; rank[i] = 0; }
    __syncthreads();
    for (int i = tid; i < cnt; i += 256) {
        int d = dst[base + i];
        atomicAdd(&hist[d >> NBSHIFT], 1);
    }
    __syncthreads();
    // inclusive scan over 512 (Hillis-Steele, 2 elems/thread, read-old then write)
    scanned[tid] = hist[tid]; scanned[tid + 256] = hist[tid + 256];
    __syncthreads();
    for (int off = 1; off < 512; off <<= 1) {
        int i0 = tid, i1 = tid + 256;
        int v0 = (i0 >= off) ? scanned[i0 - off] : 0;
        int v1 = (i1 >= off) ? scanned[i1 - off] : 0;
        __syncthreads();
        scanned[i0] += v0; scanned[i1] += v1;
        __syncthreads();
    }
    // rank pass: re-read edges (L2-hot), place into LDS grouped by bin
    for (int i = tid; i < cnt; i += 256) {
        int d = dst[base + i];
        int s = src[base + i];
        int b = d >> NBSHIFT;
        unsigned int p = (unsigned int)s | ((unsigned int)(d & 255) << 17);
        int r = atomicAdd(&rank[b], 1);
        int pos = scanned[b] - hist[b] + r;
        pk[pos] = p;
        binOf[pos] = (unsigned short)b;
    }
    __syncthreads();
    // global reserve: one atomic per non-empty bin
    for (int b = tid; b < nbins; b += 256)
        if (hist[b] > 0) gbase[b] = atomicAdd(&bin_cursor[b], hist[b]);
    __syncthreads();
    // copy out contiguous runs
    for (int i = tid; i < cnt; i += 256) {
        int b = binOf[i];
        int local = i - (scanned[b] - hist[b]);
        bpairs[gbase[b] + local] = pk[i];
    }
}

// ---------------- phase C: per-bin fine scatter (one block per bin) ----------------
__global__ __launch_bounds__(256) void binscatter_kernel(const unsigned int* __restrict__ bpairs,
                                                         const int* __restrict__ bin_base,
                                                         int* __restrict__ cursor,
                                                         int* __restrict__ ssrc) {
    int b = blockIdx.x;
    int start = bin_base[b], end = bin_base[b + 1];
    int dhigh = b << NBSHIFT;
    for (int i = start + threadIdx.x; i < end; i += 256) {
        unsigned int p = bpairs[i];
        int s = (int)(p & 0x1FFFFu);
        int d = dhigh | (int)(p >> 17);
        int pos = atomicAdd(&cursor[d], 1);
        ssrc[pos] = s;
    }
}

// ---------------- W1 transpose + cast: [512,128] f32 -> [128,512] bf16 ----------------
__global__ void w1cast_kernel(const float* __restrict__ W1, unsigned short* __restrict__ W1t) {
    int idx = blockIdx.x * 256 + threadIdx.x;  // 65536
    int k = idx >> 7, n = idx & 127;
    W1t[n * 512 + k] = f2bf(W1[idx]);
}

// ---------------- GEMM1: [N,512]@[512,128], bf16 MFMA, BM=64, swizzled LDS, prefetch ----------------
#define BM 64
#define BK 64
// LDS row = 64 bf16 = 128 B = 8 chunks of 16B; chunk c stored at c ^ (row & 7)

__global__ __launch_bounds__(256) void gemm1_mfma_kernel(const float* __restrict__ X,
                                                         const unsigned short* __restrict__ W1t,
                                                         float* __restrict__ H, int N) {
    __shared__ unsigned short As[BM * 64];    // 8 KB
    __shared__ unsigned short Bs[128 * 64];   // 16 KB
    int tid = threadIdx.x;
    int wave = tid >> 6, lane = tid & 63;
    int quad = lane >> 4, lr = lane & 15;
    int mBase = (wave & 1) * 32, nBase = (wave >> 1) * 64;
    int rowBase = blockIdx.x * BM;

    v4f zero4 = {0.f, 0.f, 0.f, 0.f};
    v4f acc[2][4];
    #pragma unroll
    for (int i = 0; i < 2; i++)
        #pragma unroll
        for (int j = 0; j < 4; j++) acc[i][j] = zero4;

    float4 pfA[4];
    uint4  pfB[4];

    // prefetch helpers (indices recomputed; compiler folds)
    #define LOAD_A(K0)                                                             \
        _Pragma("unroll")                                                          \
        for (int t = 0; t < 4; t++) {                                              \
            int idx = tid + t * 256;                                               \
            int r = idx >> 4, f4 = idx & 15;                                       \
            int gr = rowBase + r;                                                  \
            pfA[t] = (gr < N) ? *(const float4*)(X + (size_t)gr * 512 + (K0) + f4 * 4) \
                              : make_float4(0.f, 0.f, 0.f, 0.f);                   \
        }
    #define LOAD_B(K0)                                                             \
        _Pragma("unroll")                                                          \
        for (int t = 0; t < 4; t++) {                                              \
            int idx = tid + t * 256;                                               \
            int n = idx >> 3, c = idx & 7;                                         \
            pfB[t] = *(const uint4*)(W1t + (size_t)n * 512 + (K0) + c * 8);        \
        }

    LOAD_A(0); LOAD_B(0);

    for (int k0 = 0; k0 < 512; k0 += BK) {
        __syncthreads();  // LDS safe to overwrite
        // store A (f32->bf16), 8B per thread-item, swizzled
        #pragma unroll
        for (int t = 0; t < 4; t++) {
            int idx = tid + t * 256;
            int r = idx >> 4, f4 = idx & 15;
            int c = f4 >> 1, half = f4 & 1;
            ushort4 b;
            b.x = f2bf(pfA[t].x); b.y = f2bf(pfA[t].y);
            b.z = f2bf(pfA[t].z); b.w = f2bf(pfA[t].w);
            *(ushort4*)(&As[r * 64 + ((c ^ (r & 7)) << 3) + half * 4]) = b;
        }
        // store B, 16B per thread-item, swizzled
        #pragma unroll
        for (int t = 0; t < 4; t++) {
            int idx = tid + t * 256;
            int n = idx >> 3, c = idx & 7;
            *(uint4*)(&Bs[n * 64 + ((c ^ (n & 7)) << 3)]) = pfB[t];
        }
        __syncthreads();
        if (k0 + BK < 512) { LOAD_A(k0 + BK); LOAD_B(k0 + BK); }
        #pragma unroll
        for (int kc = 0; kc < BK; kc += 32) {
            int cb = kc >> 3;  // base chunk (0 or 4)
            short8 aF[2], bF[4];
            #pragma unroll
            for (int i = 0; i < 2; i++) {
                int m = mBase + i * 16 + lr;
                aF[i] = *(const short8*)(&As[m * 64 + (((cb + quad) ^ (m & 7)) << 3)]);
            }
            #pragma unroll
            for (int j = 0; j < 4; j++) {
                int n = nBase + j * 16 + lr;
                bF[j] = *(const short8*)(&Bs[n * 64 + (((cb + quad) ^ (n & 7)) << 3)]);
            }
            #pragma unroll
            for (int i = 0; i < 2; i++)
                #pragma unroll
                for (int j = 0; j < 4; j++)
                    acc[i][j] = __builtin_amdgcn_mfma_f32_16x16x32_bf16(aF[i], bF[j], acc[i][j], 0, 0, 0);
        }
    }
    // epilogue: C/D col=lane&15, row=quad*4+reg
    #pragma unroll
    for (int i = 0; i < 2; i++) {
        #pragma unroll
        for (int r = 0; r < 4; r++) {
            int m = rowBase + mBase + i * 16 + quad * 4 + r;
            if (m < N) {
                #pragma unroll
                for (int j = 0; j < 4; j++)
                    H[(size_t)m * 128 + nBase + j * 16 + lr] = acc[i][j][r];
            }
        }
    }
    #undef LOAD_A
    #undef LOAD_B
}

// ---------------- Agg1: 32 threads/node, float4/lane, unroll 4 ----------------
__global__ __launch_bounds__(256) void agg1_kernel(const float* __restrict__ h1,
                                                   const int* __restrict__ offsets,
                                                   const int* __restrict__ ssrc,
                                                   const float* __restrict__ dinv,
                                                   const float* __restrict__ bias,
                                                   float* __restrict__ a1, int N) {
    int lane = threadIdx.x & 31;
    int node = (blockIdx.x << 3) + (threadIdx.x >> 5);
    if (node >= N) return;
    float di = dinv[node];
    const float4* h = (const float4*)h1;
    float4 v = h[(size_t)node * 32 + lane];
    float4 acc;
    acc.x = di * v.x; acc.y = di * v.y; acc.z = di * v.z; acc.w = di * v.w;
    int e = offsets[node], e1 = offsets[node + 1];
    for (; e + 3 < e1; e += 4) {
        int sA = ssrc[e], sB = ssrc[e + 1], sC = ssrc[e + 2], sD = ssrc[e + 3];
        float wA = dinv[sA], wB = dinv[sB], wC = dinv[sC], wD = dinv[sD];
        float4 hA = h[(size_t)sA * 32 + lane];
        float4 hB = h[(size_t)sB * 32 + lane];
        float4 hC = h[(size_t)sC * 32 + lane];
        float4 hD = h[(size_t)sD * 32 + lane];
        acc.x = fmaf(wA, hA.x, acc.x); acc.y = fmaf(wA, hA.y, acc.y);
        acc.z = fmaf(wA, hA.z, acc.z); acc.w = fmaf(wA, hA.w, acc.w);
        acc.x = fmaf(wB, hB.x, acc.x); acc.y = fmaf(wB, hB.y, acc.y);
        acc.z = fmaf(wB, hB.z, acc.z); acc.w = fmaf(wB, hB.w, acc.w);
        acc.x = fmaf(wC, hC.x, acc.x); acc.y = fmaf(wC, hC.y, acc.y);
        acc.z = fmaf(wC, hC.z, acc.z); acc.w = fmaf(wC, hC.w, acc.w);
        acc.x = fmaf(wD, hD.x, acc.x); acc.y = fmaf(wD, hD.y, acc.y);
        acc.z = fmaf(wD, hD.z, acc.z); acc.w = fmaf(wD, hD.w, acc.w);
    }
    for (; e < e1; e++) {
        int s = ssrc[e];
        float w = dinv[s];
        float4 hs = h[(size_t)s * 32 + lane];
        acc.x = fmaf(w, hs.x, acc.x); acc.y = fmaf(w, hs.y, acc.y);
        acc.z = fmaf(w, hs.z, acc.z); acc.w = fmaf(w, hs.w, acc.w);
    }
    float4 b = ((const float4*)bias)[lane];
    float4 o;
    o.x = fmaxf(fmaf(di, acc.x, b.x), 0.f);
    o.y = fmaxf(fmaf(di, acc.y, b.y), 0.f);
    o.z = fmaxf(fmaf(di, acc.z, b.z), 0.f);
    o.w = fmaxf(fmaf(di, acc.w, b.w), 0.f);
    ((float4*)a1)[(size_t)node * 32 + lane] = o;
}

// ---------------- GEMM2: [N,128] @ [128,40] -> [N,40], f32 ----------------
__global__ __launch_bounds__(256) void gemm2_kernel(const float* __restrict__ A,
                                                    const float* __restrict__ W,
                                                    float* __restrict__ H, int N) {
    __shared__ float As2[128][64];
    __shared__ float Ws[128 * 40];
    int tid = threadIdx.x;
    int rowBase = blockIdx.x * 64;

    #pragma unroll
    for (int l = 0; l < 8; l++) {
        int e = tid + l * 256;
        int r = e >> 5;
        int kk = (e & 31) << 2;
        int grow = rowBase + r;
        float4 v = make_float4(0.f, 0.f, 0.f, 0.f);
        if (grow < N) v = *(const float4*)&A[grow * 128 + kk];
        As2[kk + 0][r] = v.x; As2[kk + 1][r] = v.y;
        As2[kk + 2][r] = v.z; As2[kk + 3][r] = v.w;
    }
    #pragma unroll
    for (int l = 0; l < 5; l++) {
        int e = tid + l * 256;
        *(float4*)&Ws[e << 2] = *(const float4*)&W[e << 2];
    }
    __syncthreads();

    int tx = tid & 7;
    int ty = tid >> 3;
    float acc[2][5];
    #pragma unroll
    for (int r = 0; r < 2; r++)
        #pragma unroll
        for (int c = 0; c < 5; c++) acc[r][c] = 0.f;

    #pragma unroll 8
    for (int k = 0; k < 128; k++) {
        float a0 = As2[k][ty * 2];
        float a1v = As2[k][ty * 2 + 1];
        #pragma unroll
        for (int c = 0; c < 5; c++) {
            float w = Ws[k * 40 + tx * 5 + c];
            acc[0][c] = fmaf(a0, w, acc[0][c]);
            acc[1][c] = fmaf(a1v, w, acc[1][c]);
        }
    }
    #pragma unroll
    for (int r = 0; r < 2; r++) {
        int grow = rowBase + ty * 2 + r;
        if (grow < N) {
            #pragma unroll
            for (int c = 0; c < 5; c++) H[grow * 40 + tx * 5 + c] = acc[r][c];
        }
    }
}

// ---------------- Agg2 + bias + log_softmax ----------------
__global__ __launch_bounds__(256) void agg2_kernel(const float* __restrict__ h2,
                                                   const int* __restrict__ offsets,
                                                   const int* __restrict__ ssrc,
                                                   const float* __restrict__ dinv,
                                                   const float* __restrict__ bias,
                                                   float* __restrict__ out, int N) {
    int node = blockIdx.x * 4 + (threadIdx.x >> 6);
    int lane = threadIdx.x & 63;
    if (node >= N) return;
    float di = dinv[node];
    bool act = lane < 40;
    float acc = 0.f;
    if (act) acc = di * h2[(size_t)node * 40 + lane];
    int e = offsets[node], e1 = offsets[node + 1];
    for (; e + 3 < e1; e += 4) {
        int sa = ssrc[e], sb = ssrc[e + 1], sc = ssrc[e + 2], sd = ssrc[e + 3];
        float wa = dinv[sa], wb = dinv[sb], wc = dinv[sc], wd = dinv[sd];
        if (act) {
            float ha = h2[(size_t)sa * 40 + lane];
            float hb = h2[(size_t)sb * 40 + lane];
            float hc = h2[(size_t)sc * 40 + lane];
            float hd = h2[(size_t)sd * 40 + lane];
            acc = fmaf(wa, ha, acc); acc = fmaf(wb, hb, acc);
            acc = fmaf(wc, hc, acc); acc = fmaf(wd, hd, acc);
        }
    }
    for (; e < e1; e++) {
        int s = ssrc[e];
        float w = dinv[s];
        if (act) acc = fmaf(w, h2[(size_t)s * 40 + lane], acc);
    }
    float v = act ? fmaf(di, acc, bias[lane]) : -INFINITY;
    float m = v;
    #pragma unroll
    for (int off = 32; off; off >>= 1) m = fmaxf(m, __shfl_xor(m, off, 64));
    float ex = act ? expf(v - m) : 0.f;
    float s = ex;
    #pragma unroll
    for (int off = 32; off; off >>= 1) s += __shfl_xor(s, off, 64);
    if (act) out[(size_t)node * 40 + lane] = v - m - logf(s);
}

// ---------------- launch ----------------
extern "C" void kernel_launch(void* const* d_in, const int* in_sizes, int n_in,
                              void* d_out, int out_size, void* d_ws, size_t ws_size,
                              hipStream_t stream) {
    const float* x  = (const float*)d_in[0];
    const int*   ei = (const int*)d_in[1];
    const float* W1 = (const float*)d_in[2];
    const float* b1 = (const float*)d_in[3];
    const float* W2 = (const float*)d_in[4];
    const float* b2 = (const float*)d_in[5];
    float* out = (float*)d_out;

    int N = in_sizes[0] / 512;
    int E = in_sizes[1] / 2;
    const int* src = ei;
    const int* dst = ei + E;
    int nbins = (N + 255) >> NBSHIFT;  // 391 for N=100000 (src fits 17 bits: N < 131072)

    char* ws = (char*)d_ws;
    size_t off = 0;
    auto alloc = [&](size_t bytes) -> void* {
        void* p = ws + off;
        off += (bytes + 255) & ~(size_t)255;
        return p;
    };
    int*   counts    = (int*)alloc((size_t)N * 4);
    int*   offsets   = (int*)alloc((size_t)(N + 1) * 4);
    int*   cursor    = (int*)alloc((size_t)N * 4);
    float* dinv      = (float*)alloc((size_t)N * 4);
    int nb = (N + SCAN_B - 1) / SCAN_B;
    int*   blockSums = (int*)alloc((size_t)nb * 4);
    int*   bin_base  = (int*)alloc((size_t)(nbins + 1) * 4);
    int*   bin_cur   = (int*)alloc((size_t)nbins * 4);
    int*   ssrc      = (int*)alloc((size_t)E * 4);
    unsigned short* W1t = (unsigned short*)alloc((size_t)128 * 512 * 2);
    float* h1        = (float*)alloc((size_t)N * 128 * 4);
    float* a1        = (float*)alloc((size_t)N * 128 * 4);
    float* h2        = (float*)alloc((size_t)N * 40 * 4);
    unsigned int* bpairs = (unsigned int*)h1;  // alias: consumed before gemm1 writes h1
    (void)ws_size; (void)n_in; (void)out_size;

    hipMemsetAsync(counts, 0, (size_t)N * 4, stream);
    count_deg_kernel<<<(E + 255) / 256, 256, 0, stream>>>(dst, E, counts);
    scan1_kernel<<<nb, SCAN_B, 0, stream>>>(counts, N, offsets, blockSums);
    scan2_kernel<<<1, 256, 0, stream>>>(blockSums, nb);
    scan3_kernel<<<nb, SCAN_B, 0, stream>>>(counts, offsets, blockSums, N, E, cursor, dinv);
    binbase_kernel<<<(nbins + 256) / 256, 256, 0, stream>>>(offsets, bin_base, bin_cur, nbins, N);
    binpass_kernel<<<(E + CHUNK - 1) / CHUNK, 256, 0, stream>>>(src, dst, E, bin_cur, bpairs, nbins);
    binscatter_kernel<<<nbins, 256, 0, stream>>>(bpairs, bin_base, cursor, ssrc);
    w1cast_kernel<<<256, 256, 0, stream>>>(W1, W1t);
    gemm1_mfma_kernel<<<(N + BM - 1) / BM, 256, 0, stream>>>(x, W1t, h1, N);
    agg1_kernel<<<(N + 7) / 8, 256, 0, stream>>>(h1, offsets, ssrc, dinv, b1, a1, N);
    gemm2_kernel<<<(N + 63) / 64, 256, 0, stream>>>(a1, W2, h2, N);
    agg2_kernel<<<(N + 3) / 4, 256, 0, stream>>>(h2, offsets, ssrc, dinv, b2, out, N);
}

// Round 5
// 661.622 us; speedup vs baseline: 1.5023x; 1.1109x over previous
//
#include <hip/hip_runtime.h>
#include <math.h>

#define SCAN_B 512
#define NBSHIFT 8
#define CHUNK 8192

typedef __attribute__((ext_vector_type(8))) short short8;
typedef __attribute__((ext_vector_type(4))) float v4f;

__device__ __forceinline__ unsigned short f2bf(float f) {
    unsigned int u = __float_as_uint(f);
    u += 0x7FFFu + ((u >> 16) & 1u);  // RNE
    return (unsigned short)(u >> 16);
}
__device__ __forceinline__ unsigned int packbf(float a, float b) {
    return (unsigned int)f2bf(a) | ((unsigned int)f2bf(b) << 16);
}
__device__ __forceinline__ void bf8_to_f32(uint4 v, float* f) {
    f[0] = __uint_as_float(v.x << 16); f[1] = __uint_as_float(v.x & 0xFFFF0000u);
    f[2] = __uint_as_float(v.y << 16); f[3] = __uint_as_float(v.y & 0xFFFF0000u);
    f[4] = __uint_as_float(v.z << 16); f[5] = __uint_as_float(v.z & 0xFFFF0000u);
    f[6] = __uint_as_float(v.w << 16); f[7] = __uint_as_float(v.w & 0xFFFF0000u);
}

// ---------------- degree count ----------------
__global__ void count_deg_kernel(const int* __restrict__ dst, int E, int* __restrict__ counts) {
    int e = blockIdx.x * blockDim.x + threadIdx.x;
    if (e < E) atomicAdd(&counts[dst[e]], 1);
}

// ---------------- exclusive scan (3-phase) ----------------
__global__ void scan1_kernel(const int* __restrict__ counts, int N,
                             int* __restrict__ partial, int* __restrict__ blockSums) {
    __shared__ int sm[SCAN_B];
    int tid = threadIdx.x;
    int i = blockIdx.x * SCAN_B + tid;
    int v = (i < N) ? counts[i] : 0;
    sm[tid] = v;
    __syncthreads();
    for (int off = 1; off < SCAN_B; off <<= 1) {
        int t = (tid >= off) ? sm[tid - off] : 0;
        __syncthreads();
        sm[tid] += t;
        __syncthreads();
    }
    if (i < N) partial[i] = sm[tid] - v;
    if (tid == SCAN_B - 1) blockSums[blockIdx.x] = sm[tid];
}

__global__ void scan2_kernel(int* __restrict__ blockSums, int nb) {
    __shared__ int sm[256];
    int tid = threadIdx.x;
    int v = (tid < nb) ? blockSums[tid] : 0;
    sm[tid] = v;
    __syncthreads();
    for (int off = 1; off < 256; off <<= 1) {
        int t = (tid >= off) ? sm[tid - off] : 0;
        __syncthreads();
        sm[tid] += t;
        __syncthreads();
    }
    if (tid < nb) blockSums[tid] = sm[tid] - v;
}

__global__ void scan3_kernel(const int* __restrict__ counts, int* __restrict__ offsets,
                             const int* __restrict__ blockSums, int N, int E,
                             int* __restrict__ cursor, float* __restrict__ dinv) {
    int i = blockIdx.x * SCAN_B + threadIdx.x;
    if (i < N) {
        int off = offsets[i] + blockSums[blockIdx.x];
        offsets[i] = off;
        cursor[i] = off;
        dinv[i] = rsqrtf((float)(counts[i] + 1));
    }
    if (i == 0 && blockIdx.x == 0) offsets[N] = E;
}

// ---------------- bin bases ----------------
__global__ void binbase_kernel(const int* __restrict__ offsets, int* __restrict__ bin_base,
                               int* __restrict__ bin_cursor, int nbins, int N) {
    int b = blockIdx.x * 256 + threadIdx.x;
    if (b <= nbins) {
        int node = b << NBSHIFT;
        if (node > N) node = N;
        bin_base[b] = offsets[node];
        if (b < nbins) bin_cursor[b] = offsets[node];
    }
}

// ---------------- phase B: local counting-sort into coarse bins ----------------
__global__ __launch_bounds__(256) void binpass_kernel(const int* __restrict__ src,
                                                      const int* __restrict__ dst, int E,
                                                      int* __restrict__ bin_cursor,
                                                      unsigned int* __restrict__ bpairs, int nbins) {
    __shared__ unsigned int pk[CHUNK];
    __shared__ unsigned short binOf[CHUNK];
    __shared__ int hist[512];
    __shared__ int scanned[512];
    __shared__ int rank[512];
    __shared__ int gbase[512];
    int tid = threadIdx.x;
    int base = blockIdx.x * CHUNK;
    int cnt = E - base; if (cnt > CHUNK) cnt = CHUNK;

    for (int i = tid; i < 512; i += 256) { hist[i] = 0; rank[i] = 0; }
    __syncthreads();
    for (int i = tid; i < cnt; i += 256) {
        int d = dst[base + i];
        atomicAdd(&hist[d >> NBSHIFT], 1);
    }
    __syncthreads();
    scanned[tid] = hist[tid]; scanned[tid + 256] = hist[tid + 256];
    __syncthreads();
    for (int off = 1; off < 512; off <<= 1) {
        int i0 = tid, i1 = tid + 256;
        int v0 = (i0 >= off) ? scanned[i0 - off] : 0;
        int v1 = (i1 >= off) ? scanned[i1 - off] : 0;
        __syncthreads();
        scanned[i0] += v0; scanned[i1] += v1;
        __syncthreads();
    }
    for (int i = tid; i < cnt; i += 256) {
        int d = dst[base + i];
        int s = src[base + i];
        int b = d >> NBSHIFT;
        unsigned int p = (unsigned int)s | ((unsigned int)(d & 255) << 17);
        int r = atomicAdd(&rank[b], 1);
        int pos = scanned[b] - hist[b] + r;
        pk[pos] = p;
        binOf[pos] = (unsigned short)b;
    }
    __syncthreads();
    for (int b = tid; b < nbins; b += 256)
        if (hist[b] > 0) gbase[b] = atomicAdd(&bin_cursor[b], hist[b]);
    __syncthreads();
    for (int i = tid; i < cnt; i += 256) {
        int b = binOf[i];
        int local = i - (scanned[b] - hist[b]);
        bpairs[gbase[b] + local] = pk[i];
    }
}

// ---------------- phase C: per-bin fine scatter ----------------
__global__ __launch_bounds__(256) void binscatter_kernel(const unsigned int* __restrict__ bpairs,
                                                         const int* __restrict__ bin_base,
                                                         int* __restrict__ cursor,
                                                         int* __restrict__ ssrc) {
    int b = blockIdx.x;
    int start = bin_base[b], end = bin_base[b + 1];
    int dhigh = b << NBSHIFT;
    for (int i = start + threadIdx.x; i < end; i += 256) {
        unsigned int p = bpairs[i];
        int s = (int)(p & 0x1FFFFu);
        int d = dhigh | (int)(p >> 17);
        int pos = atomicAdd(&cursor[d], 1);
        ssrc[pos] = s;
    }
}

// ---------------- W1 transpose + cast ----------------
__global__ void w1cast_kernel(const float* __restrict__ W1, unsigned short* __restrict__ W1t) {
    int idx = blockIdx.x * 256 + threadIdx.x;
    int k = idx >> 7, n = idx & 127;
    W1t[n * 512 + k] = f2bf(W1[idx]);
}

// ---------------- GEMM1: [N,512]@[512,128], bf16 MFMA, bf16 output ----------------
#define BM 64
#define BK 64

__global__ __launch_bounds__(256) void gemm1_mfma_kernel(const float* __restrict__ X,
                                                         const unsigned short* __restrict__ W1t,
                                                         unsigned short* __restrict__ H, int N) {
    __shared__ unsigned short As[BM * 64];
    __shared__ unsigned short Bs[128 * 64];
    int tid = threadIdx.x;
    int wave = tid >> 6, lane = tid & 63;
    int quad = lane >> 4, lr = lane & 15;
    int mBase = (wave & 1) * 32, nBase = (wave >> 1) * 64;
    int rowBase = blockIdx.x * BM;

    v4f zero4 = {0.f, 0.f, 0.f, 0.f};
    v4f acc[2][4];
    #pragma unroll
    for (int i = 0; i < 2; i++)
        #pragma unroll
        for (int j = 0; j < 4; j++) acc[i][j] = zero4;

    float4 pfA[4];
    uint4  pfB[4];

    #define LOAD_A(K0)                                                             \
        _Pragma("unroll")                                                          \
        for (int t = 0; t < 4; t++) {                                              \
            int idx = tid + t * 256;                                               \
            int r = idx >> 4, f4 = idx & 15;                                       \
            int gr = rowBase + r;                                                  \
            pfA[t] = (gr < N) ? *(const float4*)(X + (size_t)gr * 512 + (K0) + f4 * 4) \
                              : make_float4(0.f, 0.f, 0.f, 0.f);                   \
        }
    #define LOAD_B(K0)                                                             \
        _Pragma("unroll")                                                          \
        for (int t = 0; t < 4; t++) {                                              \
            int idx = tid + t * 256;                                               \
            int n = idx >> 3, c = idx & 7;                                         \
            pfB[t] = *(const uint4*)(W1t + (size_t)n * 512 + (K0) + c * 8);        \
        }

    LOAD_A(0); LOAD_B(0);

    for (int k0 = 0; k0 < 512; k0 += BK) {
        __syncthreads();
        #pragma unroll
        for (int t = 0; t < 4; t++) {
            int idx = tid + t * 256;
            int r = idx >> 4, f4 = idx & 15;
            int c = f4 >> 1, half = f4 & 1;
            ushort4 b;
            b.x = f2bf(pfA[t].x); b.y = f2bf(pfA[t].y);
            b.z = f2bf(pfA[t].z); b.w = f2bf(pfA[t].w);
            *(ushort4*)(&As[r * 64 + ((c ^ (r & 7)) << 3) + half * 4]) = b;
        }
        #pragma unroll
        for (int t = 0; t < 4; t++) {
            int idx = tid + t * 256;
            int n = idx >> 3, c = idx & 7;
            *(uint4*)(&Bs[n * 64 + ((c ^ (n & 7)) << 3)]) = pfB[t];
        }
        __syncthreads();
        if (k0 + BK < 512) { LOAD_A(k0 + BK); LOAD_B(k0 + BK); }
        #pragma unroll
        for (int kc = 0; kc < BK; kc += 32) {
            int cb = kc >> 3;
            short8 aF[2], bF[4];
            #pragma unroll
            for (int i = 0; i < 2; i++) {
                int m = mBase + i * 16 + lr;
                aF[i] = *(const short8*)(&As[m * 64 + (((cb + quad) ^ (m & 7)) << 3)]);
            }
            #pragma unroll
            for (int j = 0; j < 4; j++) {
                int n = nBase + j * 16 + lr;
                bF[j] = *(const short8*)(&Bs[n * 64 + (((cb + quad) ^ (n & 7)) << 3)]);
            }
            #pragma unroll
            for (int i = 0; i < 2; i++)
                #pragma unroll
                for (int j = 0; j < 4; j++)
                    acc[i][j] = __builtin_amdgcn_mfma_f32_16x16x32_bf16(aF[i], bF[j], acc[i][j], 0, 0, 0);
        }
    }
    // epilogue: bf16 stores. C/D col=lane&15, row=quad*4+reg
    #pragma unroll
    for (int i = 0; i < 2; i++) {
        #pragma unroll
        for (int r = 0; r < 4; r++) {
            int m = rowBase + mBase + i * 16 + quad * 4 + r;
            if (m < N) {
                #pragma unroll
                for (int j = 0; j < 4; j++)
                    H[(size_t)m * 128 + nBase + j * 16 + lr] = f2bf(acc[i][j][r]);
            }
        }
    }
    #undef LOAD_A
    #undef LOAD_B
}

// ---------------- Agg1: bf16 gather, 16 lanes/node, f32 accumulate, bf16 out ----------------
__global__ __launch_bounds__(256) void agg1_kernel(const unsigned short* __restrict__ h1,
                                                   const int* __restrict__ offsets,
                                                   const int* __restrict__ ssrc,
                                                   const float* __restrict__ dinv,
                                                   const float* __restrict__ bias,
                                                   unsigned short* __restrict__ a1, int N) {
    int lane = threadIdx.x & 15;
    int node = (blockIdx.x << 4) + (threadIdx.x >> 4);
    if (node >= N) return;
    const uint4* h = (const uint4*)h1;  // row = 16 uint4 (128 bf16)
    float di = dinv[node];
    float acc[8], t[8];
    bf8_to_f32(h[(size_t)node * 16 + lane], t);
    #pragma unroll
    for (int i = 0; i < 8; i++) acc[i] = di * t[i];
    int e = offsets[node], e1 = offsets[node + 1];
    for (; e + 3 < e1; e += 4) {
        int sA = ssrc[e], sB = ssrc[e + 1], sC = ssrc[e + 2], sD = ssrc[e + 3];
        float wA = dinv[sA], wB = dinv[sB], wC = dinv[sC], wD = dinv[sD];
        uint4 vA = h[(size_t)sA * 16 + lane];
        uint4 vB = h[(size_t)sB * 16 + lane];
        uint4 vC = h[(size_t)sC * 16 + lane];
        uint4 vD = h[(size_t)sD * 16 + lane];
        float fA[8], fB[8], fC[8], fD[8];
        bf8_to_f32(vA, fA); bf8_to_f32(vB, fB); bf8_to_f32(vC, fC); bf8_to_f32(vD, fD);
        #pragma unroll
        for (int i = 0; i < 8; i++) {
            acc[i] = fmaf(wA, fA[i], acc[i]);
            acc[i] = fmaf(wB, fB[i], acc[i]);
            acc[i] = fmaf(wC, fC[i], acc[i]);
            acc[i] = fmaf(wD, fD[i], acc[i]);
        }
    }
    for (; e < e1; e++) {
        int s = ssrc[e];
        float w = dinv[s];
        float fs[8];
        bf8_to_f32(h[(size_t)s * 16 + lane], fs);
        #pragma unroll
        for (int i = 0; i < 8; i++) acc[i] = fmaf(w, fs[i], acc[i]);
    }
    float4 b0 = ((const float4*)bias)[lane * 2];
    float4 b1v = ((const float4*)bias)[lane * 2 + 1];
    float bb[8] = {b0.x, b0.y, b0.z, b0.w, b1v.x, b1v.y, b1v.z, b1v.w};
    float o[8];
    #pragma unroll
    for (int i = 0; i < 8; i++) o[i] = fmaxf(fmaf(di, acc[i], bb[i]), 0.f);
    uint4 pv;
    pv.x = packbf(o[0], o[1]); pv.y = packbf(o[2], o[3]);
    pv.z = packbf(o[4], o[5]); pv.w = packbf(o[6], o[7]);
    ((uint4*)a1)[(size_t)node * 16 + lane] = pv;
}

// ---------------- GEMM2: [N,128](bf16) @ [128,40] -> [N,40] f32 ----------------
__global__ __launch_bounds__(256) void gemm2_kernel(const unsigned short* __restrict__ A,
                                                    const float* __restrict__ W,
                                                    float* __restrict__ H, int N) {
    __shared__ float As2[128][64];   // [k][m], 32 KB
    __shared__ float Ws[128 * 40];
    int tid = threadIdx.x;
    int rowBase = blockIdx.x * 64;

    // stage A: 64 rows x 128 k bf16 = 1024 uint4, 4/thread; expand to f32
    #pragma unroll
    for (int l = 0; l < 4; l++) {
        int e = tid + l * 256;
        int r = e >> 4;            // 16 uint4 per row
        int kk = (e & 15) << 3;    // 8 bf16 per uint4
        int grow = rowBase + r;
        float f[8] = {0.f, 0.f, 0.f, 0.f, 0.f, 0.f, 0.f, 0.f};
        if (grow < N) {
            uint4 v = *(const uint4*)(A + (size_t)grow * 128 + kk);
            bf8_to_f32(v, f);
        }
        #pragma unroll
        for (int q = 0; q < 8; q++) As2[kk + q][r] = f[q];
    }
    #pragma unroll
    for (int l = 0; l < 5; l++) {
        int e = tid + l * 256;
        *(float4*)&Ws[e << 2] = *(const float4*)&W[e << 2];
    }
    __syncthreads();

    int tx = tid & 7;
    int ty = tid >> 3;
    float acc[2][5];
    #pragma unroll
    for (int r = 0; r < 2; r++)
        #pragma unroll
        for (int c = 0; c < 5; c++) acc[r][c] = 0.f;

    #pragma unroll 8
    for (int k = 0; k < 128; k++) {
        float a0 = As2[k][ty * 2];
        float a1v = As2[k][ty * 2 + 1];
        #pragma unroll
        for (int c = 0; c < 5; c++) {
            float w = Ws[k * 40 + tx * 5 + c];
            acc[0][c] = fmaf(a0, w, acc[0][c]);
            acc[1][c] = fmaf(a1v, w, acc[1][c]);
        }
    }
    #pragma unroll
    for (int r = 0; r < 2; r++) {
        int grow = rowBase + ty * 2 + r;
        if (grow < N) {
            #pragma unroll
            for (int c = 0; c < 5; c++) H[grow * 40 + tx * 5 + c] = acc[r][c];
        }
    }
}

// ---------------- Agg2 + bias + log_softmax ----------------
__global__ __launch_bounds__(256) void agg2_kernel(const float* __restrict__ h2,
                                                   const int* __restrict__ offsets,
                                                   const int* __restrict__ ssrc,
                                                   const float* __restrict__ dinv,
                                                   const float* __restrict__ bias,
                                                   float* __restrict__ out, int N) {
    int node = blockIdx.x * 4 + (threadIdx.x >> 6);
    int lane = threadIdx.x & 63;
    if (node >= N) return;
    float di = dinv[node];
    bool act = lane < 40;
    float acc = 0.f;
    if (act) acc = di * h2[(size_t)node * 40 + lane];
    int e = offsets[node], e1 = offsets[node + 1];
    for (; e + 3 < e1; e += 4) {
        int sa = ssrc[e], sb = ssrc[e + 1], sc = ssrc[e + 2], sd = ssrc[e + 3];
        float wa = dinv[sa], wb = dinv[sb], wc = dinv[sc], wd = dinv[sd];
        if (act) {
            float ha = h2[(size_t)sa * 40 + lane];
            float hb = h2[(size_t)sb * 40 + lane];
            float hc = h2[(size_t)sc * 40 + lane];
            float hd = h2[(size_t)sd * 40 + lane];
            acc = fmaf(wa, ha, acc); acc = fmaf(wb, hb, acc);
            acc = fmaf(wc, hc, acc); acc = fmaf(wd, hd, acc);
        }
    }
    for (; e < e1; e++) {
        int s = ssrc[e];
        float w = dinv[s];
        if (act) acc = fmaf(w, h2[(size_t)s * 40 + lane], acc);
    }
    float v = act ? fmaf(di, acc, bias[lane]) : -INFINITY;
    float m = v;
    #pragma unroll
    for (int off = 32; off; off >>= 1) m = fmaxf(m, __shfl_xor(m, off, 64));
    float ex = act ? expf(v - m) : 0.f;
    float s = ex;
    #pragma unroll
    for (int off = 32; off; off >>= 1) s += __shfl_xor(s, off, 64);
    if (act) out[(size_t)node * 40 + lane] = v - m - logf(s);
}

// ---------------- launch ----------------
extern "C" void kernel_launch(void* const* d_in, const int* in_sizes, int n_in,
                              void* d_out, int out_size, void* d_ws, size_t ws_size,
                              hipStream_t stream) {
    const float* x  = (const float*)d_in[0];
    const int*   ei = (const int*)d_in[1];
    const float* W1 = (const float*)d_in[2];
    const float* b1 = (const float*)d_in[3];
    const float* W2 = (const float*)d_in[4];
    const float* b2 = (const float*)d_in[5];
    float* out = (float*)d_out;

    int N = in_sizes[0] / 512;
    int E = in_sizes[1] / 2;
    const int* src = ei;
    const int* dst = ei + E;
    int nbins = (N + 255) >> NBSHIFT;  // 391 (src fits 17 bits: N < 131072)

    char* ws = (char*)d_ws;
    size_t off = 0;
    auto alloc = [&](size_t bytes) -> void* {
        void* p = ws + off;
        off += (bytes + 255) & ~(size_t)255;
        return p;
    };
    int*   counts    = (int*)alloc((size_t)N * 4);
    int*   offsets   = (int*)alloc((size_t)(N + 1) * 4);
    int*   cursor    = (int*)alloc((size_t)N * 4);
    float* dinv      = (float*)alloc((size_t)N * 4);
    int nb = (N + SCAN_B - 1) / SCAN_B;
    int*   blockSums = (int*)alloc((size_t)nb * 4);
    int*   bin_base  = (int*)alloc((size_t)(nbins + 1) * 4);
    int*   bin_cur   = (int*)alloc((size_t)nbins * 4);
    int*   ssrc      = (int*)alloc((size_t)E * 4);
    unsigned short* W1t = (unsigned short*)alloc((size_t)128 * 512 * 2);
    unsigned short* h1  = (unsigned short*)alloc((size_t)N * 128 * 2);
    unsigned short* a1  = (unsigned short*)alloc((size_t)N * 128 * 2);
    float* h2        = (float*)alloc((size_t)N * 40 * 4);
    unsigned int* bpairs = (unsigned int*)h1;  // alias: E*4=6.4MB < 25.6MB, consumed pre-gemm1
    (void)ws_size; (void)n_in; (void)out_size;

    hipMemsetAsync(counts, 0, (size_t)N * 4, stream);
    count_deg_kernel<<<(E + 255) / 256, 256, 0, stream>>>(dst, E, counts);
    scan1_kernel<<<nb, SCAN_B, 0, stream>>>(counts, N, offsets, blockSums);
    scan2_kernel<<<1, 256, 0, stream>>>(blockSums, nb);
    scan3_kernel<<<nb, SCAN_B, 0, stream>>>(counts, offsets, blockSums, N, E, cursor, dinv);
    binbase_kernel<<<(nbins + 256) / 256, 256, 0, stream>>>(offsets, bin_base, bin_cur, nbins, N);
    binpass_kernel<<<(E + CHUNK - 1) / CHUNK, 256, 0, stream>>>(src, dst, E, bin_cur, bpairs, nbins);
    binscatter_kernel<<<nbins, 256, 0, stream>>>(bpairs, bin_base, cursor, ssrc);
    w1cast_kernel<<<256, 256, 0, stream>>>(W1, W1t);
    gemm1_mfma_kernel<<<(N + BM - 1) / BM, 256, 0, stream>>>(x, W1t, h1, N);
    agg1_kernel<<<(N + 15) / 16, 256, 0, stream>>>(h1, offsets, ssrc, dinv, b1, a1, N);
    gemm2_kernel<<<(N + 63) / 64, 256, 0, stream>>>(a1, W2, h2, N);
    agg2_kernel<<<(N + 3) / 4, 256, 0, stream>>>(h2, offsets, ssrc, dinv, b2, out, N);
}

// Round 6
// 660.548 us; speedup vs baseline: 1.5048x; 1.0016x over previous
//
#include <hip/hip_runtime.h>
#include <math.h>

#define SCAN_B 512
#define NBSHIFT 8
#define CHUNK 8192

typedef __attribute__((ext_vector_type(8))) short short8;
typedef __attribute__((ext_vector_type(4))) float v4f;

__device__ __forceinline__ unsigned short f2bf(float f) {
    unsigned int u = __float_as_uint(f);
    u += 0x7FFFu + ((u >> 16) & 1u);  // RNE
    return (unsigned short)(u >> 16);
}
__device__ __forceinline__ unsigned int packbf(float a, float b) {
    return (unsigned int)f2bf(a) | ((unsigned int)f2bf(b) << 16);
}
__device__ __forceinline__ void bf8_to_f32(uint4 v, float* f) {
    f[0] = __uint_as_float(v.x << 16); f[1] = __uint_as_float(v.x & 0xFFFF0000u);
    f[2] = __uint_as_float(v.y << 16); f[3] = __uint_as_float(v.y & 0xFFFF0000u);
    f[4] = __uint_as_float(v.z << 16); f[5] = __uint_as_float(v.z & 0xFFFF0000u);
    f[6] = __uint_as_float(v.w << 16); f[7] = __uint_as_float(v.w & 0xFFFF0000u);
}

// ---------------- degree count ----------------
__global__ void count_deg_kernel(const int* __restrict__ dst, int E, int* __restrict__ counts) {
    int e = blockIdx.x * blockDim.x + threadIdx.x;
    if (e < E) atomicAdd(&counts[dst[e]], 1);
}

// ---------------- exclusive scan (3-phase) ----------------
__global__ void scan1_kernel(const int* __restrict__ counts, int N,
                             int* __restrict__ partial, int* __restrict__ blockSums) {
    __shared__ int sm[SCAN_B];
    int tid = threadIdx.x;
    int i = blockIdx.x * SCAN_B + tid;
    int v = (i < N) ? counts[i] : 0;
    sm[tid] = v;
    __syncthreads();
    for (int off = 1; off < SCAN_B; off <<= 1) {
        int t = (tid >= off) ? sm[tid - off] : 0;
        __syncthreads();
        sm[tid] += t;
        __syncthreads();
    }
    if (i < N) partial[i] = sm[tid] - v;
    if (tid == SCAN_B - 1) blockSums[blockIdx.x] = sm[tid];
}

__global__ void scan2_kernel(int* __restrict__ blockSums, int nb) {
    __shared__ int sm[256];
    int tid = threadIdx.x;
    int v = (tid < nb) ? blockSums[tid] : 0;
    sm[tid] = v;
    __syncthreads();
    for (int off = 1; off < 256; off <<= 1) {
        int t = (tid >= off) ? sm[tid - off] : 0;
        __syncthreads();
        sm[tid] += t;
        __syncthreads();
    }
    if (tid < nb) blockSums[tid] = sm[tid] - v;
}

__global__ void scan3_kernel(const int* __restrict__ counts, int* __restrict__ offsets,
                             const int* __restrict__ blockSums, int N, int E,
                             int* __restrict__ cursor, float* __restrict__ dinv) {
    int i = blockIdx.x * SCAN_B + threadIdx.x;
    if (i < N) {
        int off = offsets[i] + blockSums[blockIdx.x];
        offsets[i] = off;
        cursor[i] = off;
        dinv[i] = rsqrtf((float)(counts[i] + 1));
    }
    if (i == 0 && blockIdx.x == 0) offsets[N] = E;
}

// ---------------- bin bases ----------------
__global__ void binbase_kernel(const int* __restrict__ offsets, int* __restrict__ bin_base,
                               int* __restrict__ bin_cursor, int nbins, int N) {
    int b = blockIdx.x * 256 + threadIdx.x;
    if (b <= nbins) {
        int node = b << NBSHIFT;
        if (node > N) node = N;
        bin_base[b] = offsets[node];
        if (b < nbins) bin_cursor[b] = offsets[node];
    }
}

// ---------------- phase B: local counting-sort into coarse bins ----------------
__global__ __launch_bounds__(256) void binpass_kernel(const int* __restrict__ src,
                                                      const int* __restrict__ dst, int E,
                                                      int* __restrict__ bin_cursor,
                                                      unsigned int* __restrict__ bpairs, int nbins) {
    __shared__ unsigned int pk[CHUNK];
    __shared__ unsigned short binOf[CHUNK];
    __shared__ int hist[512];
    __shared__ int scanned[512];
    __shared__ int rank[512];
    __shared__ int gbase[512];
    int tid = threadIdx.x;
    int base = blockIdx.x * CHUNK;
    int cnt = E - base; if (cnt > CHUNK) cnt = CHUNK;

    for (int i = tid; i < 512; i += 256) { hist[i] = 0; rank[i] = 0; }
    __syncthreads();
    for (int i = tid; i < cnt; i += 256) {
        int d = dst[base + i];
        atomicAdd(&hist[d >> NBSHIFT], 1);
    }
    __syncthreads();
    scanned[tid] = hist[tid]; scanned[tid + 256] = hist[tid + 256];
    __syncthreads();
    for (int off = 1; off < 512; off <<= 1) {
        int i0 = tid, i1 = tid + 256;
        int v0 = (i0 >= off) ? scanned[i0 - off] : 0;
        int v1 = (i1 >= off) ? scanned[i1 - off] : 0;
        __syncthreads();
        scanned[i0] += v0; scanned[i1] += v1;
        __syncthreads();
    }
    for (int i = tid; i < cnt; i += 256) {
        int d = dst[base + i];
        int s = src[base + i];
        int b = d >> NBSHIFT;
        unsigned int p = (unsigned int)s | ((unsigned int)(d & 255) << 17);
        int r = atomicAdd(&rank[b], 1);
        int pos = scanned[b] - hist[b] + r;
        pk[pos] = p;
        binOf[pos] = (unsigned short)b;
    }
    __syncthreads();
    for (int b = tid; b < nbins; b += 256)
        if (hist[b] > 0) gbase[b] = atomicAdd(&bin_cursor[b], hist[b]);
    __syncthreads();
    for (int i = tid; i < cnt; i += 256) {
        int b = binOf[i];
        int local = i - (scanned[b] - hist[b]);
        bpairs[gbase[b] + local] = pk[i];
    }
}

// ---------------- phase C: per-bin fine scatter ----------------
__global__ __launch_bounds__(256) void binscatter_kernel(const unsigned int* __restrict__ bpairs,
                                                         const int* __restrict__ bin_base,
                                                         int* __restrict__ cursor,
                                                         int* __restrict__ ssrc) {
    int b = blockIdx.x;
    int start = bin_base[b], end = bin_base[b + 1];
    int dhigh = b << NBSHIFT;
    for (int i = start + threadIdx.x; i < end; i += 256) {
        unsigned int p = bpairs[i];
        int s = (int)(p & 0x1FFFFu);
        int d = dhigh | (int)(p >> 17);
        int pos = atomicAdd(&cursor[d], 1);
        ssrc[pos] = s;
    }
}

// ---------------- W1 transpose + cast ----------------
__global__ void w1cast_kernel(const float* __restrict__ W1, unsigned short* __restrict__ W1t) {
    int idx = blockIdx.x * 256 + threadIdx.x;
    int k = idx >> 7, n = idx & 127;
    W1t[n * 512 + k] = f2bf(W1[idx]);
}

// ---------------- GEMM1: [N,512]@[512,128], bf16 MFMA, LDS-staged bf16 output ----------------
#define BM 64
#define BK 64

__global__ __launch_bounds__(256) void gemm1_mfma_kernel(const float* __restrict__ X,
                                                         const unsigned short* __restrict__ W1t,
                                                         unsigned short* __restrict__ H, int N) {
    __shared__ unsigned short As[BM * 64];    // 8 KB
    __shared__ unsigned short Bs[128 * 64];   // 16 KB; reused as 64x128 C tile in epilogue
    int tid = threadIdx.x;
    int wave = tid >> 6, lane = tid & 63;
    int quad = lane >> 4, lr = lane & 15;
    int mBase = (wave & 1) * 32, nBase = (wave >> 1) * 64;
    int rowBase = blockIdx.x * BM;

    v4f zero4 = {0.f, 0.f, 0.f, 0.f};
    v4f acc[2][4];
    #pragma unroll
    for (int i = 0; i < 2; i++)
        #pragma unroll
        for (int j = 0; j < 4; j++) acc[i][j] = zero4;

    float4 pfA[4];
    uint4  pfB[4];

    #define LOAD_A(K0)                                                             \
        _Pragma("unroll")                                                          \
        for (int t = 0; t < 4; t++) {                                              \
            int idx = tid + t * 256;                                               \
            int r = idx >> 4, f4 = idx & 15;                                       \
            int gr = rowBase + r;                                                  \
            pfA[t] = (gr < N) ? *(const float4*)(X + (size_t)gr * 512 + (K0) + f4 * 4) \
                              : make_float4(0.f, 0.f, 0.f, 0.f);                   \
        }
    #define LOAD_B(K0)                                                             \
        _Pragma("unroll")                                                          \
        for (int t = 0; t < 4; t++) {                                              \
            int idx = tid + t * 256;                                               \
            int n = idx >> 3, c = idx & 7;                                         \
            pfB[t] = *(const uint4*)(W1t + (size_t)n * 512 + (K0) + c * 8);        \
        }

    LOAD_A(0); LOAD_B(0);

    for (int k0 = 0; k0 < 512; k0 += BK) {
        __syncthreads();
        #pragma unroll
        for (int t = 0; t < 4; t++) {
            int idx = tid + t * 256;
            int r = idx >> 4, f4 = idx & 15;
            int c = f4 >> 1, half = f4 & 1;
            ushort4 b;
            b.x = f2bf(pfA[t].x); b.y = f2bf(pfA[t].y);
            b.z = f2bf(pfA[t].z); b.w = f2bf(pfA[t].w);
            *(ushort4*)(&As[r * 64 + ((c ^ (r & 7)) << 3) + half * 4]) = b;
        }
        #pragma unroll
        for (int t = 0; t < 4; t++) {
            int idx = tid + t * 256;
            int n = idx >> 3, c = idx & 7;
            *(uint4*)(&Bs[n * 64 + ((c ^ (n & 7)) << 3)]) = pfB[t];
        }
        __syncthreads();
        if (k0 + BK < 512) { LOAD_A(k0 + BK); LOAD_B(k0 + BK); }
        #pragma unroll
        for (int kc = 0; kc < BK; kc += 32) {
            int cb = kc >> 3;
            short8 aF[2], bF[4];
            #pragma unroll
            for (int i = 0; i < 2; i++) {
                int m = mBase + i * 16 + lr;
                aF[i] = *(const short8*)(&As[m * 64 + (((cb + quad) ^ (m & 7)) << 3)]);
            }
            #pragma unroll
            for (int j = 0; j < 4; j++) {
                int n = nBase + j * 16 + lr;
                bF[j] = *(const short8*)(&Bs[n * 64 + (((cb + quad) ^ (n & 7)) << 3)]);
            }
            #pragma unroll
            for (int i = 0; i < 2; i++)
                #pragma unroll
                for (int j = 0; j < 4; j++)
                    acc[i][j] = __builtin_amdgcn_mfma_f32_16x16x32_bf16(aF[i], bF[j], acc[i][j], 0, 0, 0);
        }
    }
    // ---- epilogue: stage C tile (64x128 bf16 = 16 KB) in Bs, then stream out ----
    __syncthreads();  // all MFMA reads of Bs done
    unsigned short* Cs = Bs;
    #pragma unroll
    for (int i = 0; i < 2; i++) {
        #pragma unroll
        for (int r = 0; r < 4; r++) {
            int m = mBase + i * 16 + quad * 4 + r;  // local row 0..63
            #pragma unroll
            for (int j = 0; j < 4; j++)
                Cs[m * 128 + nBase + j * 16 + lr] = f2bf(acc[i][j][r]);
        }
    }
    __syncthreads();
    #pragma unroll
    for (int t = 0; t < 4; t++) {
        int idx = tid + t * 256;          // 0..1023
        int row = idx >> 4, c = idx & 15; // 16 uint4 per 128-col row
        int gr = rowBase + row;
        if (gr < N)
            *(uint4*)(H + (size_t)gr * 128 + c * 8) = *(const uint4*)(Cs + row * 128 + c * 8);
    }
    #undef LOAD_A
    #undef LOAD_B
}

// ---------------- Agg1: bf16 gather, 16 lanes/node, f32 accumulate, bf16 out ----------------
__global__ __launch_bounds__(256) void agg1_kernel(const unsigned short* __restrict__ h1,
                                                   const int* __restrict__ offsets,
                                                   const int* __restrict__ ssrc,
                                                   const float* __restrict__ dinv,
                                                   const float* __restrict__ bias,
                                                   unsigned short* __restrict__ a1, int N) {
    int lane = threadIdx.x & 15;
    int node = (blockIdx.x << 4) + (threadIdx.x >> 4);
    if (node >= N) return;
    const uint4* h = (const uint4*)h1;  // row = 16 uint4 (128 bf16)
    float di = dinv[node];
    float acc[8], t[8];
    bf8_to_f32(h[(size_t)node * 16 + lane], t);
    #pragma unroll
    for (int i = 0; i < 8; i++) acc[i] = di * t[i];
    int e = offsets[node], e1 = offsets[node + 1];
    for (; e + 3 < e1; e += 4) {
        int sA = ssrc[e], sB = ssrc[e + 1], sC = ssrc[e + 2], sD = ssrc[e + 3];
        float wA = dinv[sA], wB = dinv[sB], wC = dinv[sC], wD = dinv[sD];
        uint4 vA = h[(size_t)sA * 16 + lane];
        uint4 vB = h[(size_t)sB * 16 + lane];
        uint4 vC = h[(size_t)sC * 16 + lane];
        uint4 vD = h[(size_t)sD * 16 + lane];
        float fA[8], fB[8], fC[8], fD[8];
        bf8_to_f32(vA, fA); bf8_to_f32(vB, fB); bf8_to_f32(vC, fC); bf8_to_f32(vD, fD);
        #pragma unroll
        for (int i = 0; i < 8; i++) {
            acc[i] = fmaf(wA, fA[i], acc[i]);
            acc[i] = fmaf(wB, fB[i], acc[i]);
            acc[i] = fmaf(wC, fC[i], acc[i]);
            acc[i] = fmaf(wD, fD[i], acc[i]);
        }
    }
    for (; e < e1; e++) {
        int s = ssrc[e];
        float w = dinv[s];
        float fs[8];
        bf8_to_f32(h[(size_t)s * 16 + lane], fs);
        #pragma unroll
        for (int i = 0; i < 8; i++) acc[i] = fmaf(w, fs[i], acc[i]);
    }
    float4 b0 = ((const float4*)bias)[lane * 2];
    float4 b1v = ((const float4*)bias)[lane * 2 + 1];
    float bb[8] = {b0.x, b0.y, b0.z, b0.w, b1v.x, b1v.y, b1v.z, b1v.w};
    float o[8];
    #pragma unroll
    for (int i = 0; i < 8; i++) o[i] = fmaxf(fmaf(di, acc[i], bb[i]), 0.f);
    uint4 pv;
    pv.x = packbf(o[0], o[1]); pv.y = packbf(o[2], o[3]);
    pv.z = packbf(o[4], o[5]); pv.w = packbf(o[6], o[7]);
    ((uint4*)a1)[(size_t)node * 16 + lane] = pv;
}

// ---------------- GEMM2: [N,128](bf16) @ [128,40] -> [N,40] f32 ----------------
__global__ __launch_bounds__(256) void gemm2_kernel(const unsigned short* __restrict__ A,
                                                    const float* __restrict__ W,
                                                    float* __restrict__ H, int N) {
    __shared__ float As2[128][64];   // [k][m], 32 KB
    __shared__ float Ws[128 * 40];
    int tid = threadIdx.x;
    int rowBase = blockIdx.x * 64;

    #pragma unroll
    for (int l = 0; l < 4; l++) {
        int e = tid + l * 256;
        int r = e >> 4;            // 16 uint4 per row
        int kk = (e & 15) << 3;    // 8 bf16 per uint4
        int grow = rowBase + r;
        float f[8] = {0.f, 0.f, 0.f, 0.f, 0.f, 0.f, 0.f, 0.f};
        if (grow < N) {
            uint4 v = *(const uint4*)(A + (size_t)grow * 128 + kk);
            bf8_to_f32(v, f);
        }
        #pragma unroll
        for (int q = 0; q < 8; q++) As2[kk + q][r] = f[q];
    }
    #pragma unroll
    for (int l = 0; l < 5; l++) {
        int e = tid + l * 256;
        *(float4*)&Ws[e << 2] = *(const float4*)&W[e << 2];
    }
    __syncthreads();

    int tx = tid & 7;
    int ty = tid >> 3;
    float acc[2][5];
    #pragma unroll
    for (int r = 0; r < 2; r++)
        #pragma unroll
        for (int c = 0; c < 5; c++) acc[r][c] = 0.f;

    #pragma unroll 8
    for (int k = 0; k < 128; k++) {
        float a0 = As2[k][ty * 2];
        float a1v = As2[k][ty * 2 + 1];
        #pragma unroll
        for (int c = 0; c < 5; c++) {
            float w = Ws[k * 40 + tx * 5 + c];
            acc[0][c] = fmaf(a0, w, acc[0][c]);
            acc[1][c] = fmaf(a1v, w, acc[1][c]);
        }
    }
    #pragma unroll
    for (int r = 0; r < 2; r++) {
        int grow = rowBase + ty * 2 + r;
        if (grow < N) {
            #pragma unroll
            for (int c = 0; c < 5; c++) H[grow * 40 + tx * 5 + c] = acc[r][c];
        }
    }
}

// ---------------- Agg2 + bias + log_softmax ----------------
__global__ __launch_bounds__(256) void agg2_kernel(const float* __restrict__ h2,
                                                   const int* __restrict__ offsets,
                                                   const int* __restrict__ ssrc,
                                                   const float* __restrict__ dinv,
                                                   const float* __restrict__ bias,
                                                   float* __restrict__ out, int N) {
    int node = blockIdx.x * 4 + (threadIdx.x >> 6);
    int lane = threadIdx.x & 63;
    if (node >= N) return;
    float di = dinv[node];
    bool act = lane < 40;
    float acc = 0.f;
    if (act) acc = di * h2[(size_t)node * 40 + lane];
    int e = offsets[node], e1 = offsets[node + 1];
    for (; e + 3 < e1; e += 4) {
        int sa = ssrc[e], sb = ssrc[e + 1], sc = ssrc[e + 2], sd = ssrc[e + 3];
        float wa = dinv[sa], wb = dinv[sb], wc = dinv[sc], wd = dinv[sd];
        if (act) {
            float ha = h2[(size_t)sa * 40 + lane];
            float hb = h2[(size_t)sb * 40 + lane];
            float hc = h2[(size_t)sc * 40 + lane];
            float hd = h2[(size_t)sd * 40 + lane];
            acc = fmaf(wa, ha, acc); acc = fmaf(wb, hb, acc);
            acc = fmaf(wc, hc, acc); acc = fmaf(wd, hd, acc);
        }
    }
    for (; e < e1; e++) {
        int s = ssrc[e];
        float w = dinv[s];
        if (act) acc = fmaf(w, h2[(size_t)s * 40 + lane], acc);
    }
    float v = act ? fmaf(di, acc, bias[lane]) : -INFINITY;
    float m = v;
    #pragma unroll
    for (int off = 32; off; off >>= 1) m = fmaxf(m, __shfl_xor(m, off, 64));
    float ex = act ? expf(v - m) : 0.f;
    float s = ex;
    #pragma unroll
    for (int off = 32; off; off >>= 1) s += __shfl_xor(s, off, 64);
    if (act) out[(size_t)node * 40 + lane] = v - m - logf(s);
}

// ---------------- launch ----------------
extern "C" void kernel_launch(void* const* d_in, const int* in_sizes, int n_in,
                              void* d_out, int out_size, void* d_ws, size_t ws_size,
                              hipStream_t stream) {
    const float* x  = (const float*)d_in[0];
    const int*   ei = (const int*)d_in[1];
    const float* W1 = (const float*)d_in[2];
    const float* b1 = (const float*)d_in[3];
    const float* W2 = (const float*)d_in[4];
    const float* b2 = (const float*)d_in[5];
    float* out = (float*)d_out;

    int N = in_sizes[0] / 512;
    int E = in_sizes[1] / 2;
    const int* src = ei;
    const int* dst = ei + E;
    int nbins = (N + 255) >> NBSHIFT;  // 391 (src fits 17 bits: N < 131072)

    char* ws = (char*)d_ws;
    size_t off = 0;
    auto alloc = [&](size_t bytes) -> void* {
        void* p = ws + off;
        off += (bytes + 255) & ~(size_t)255;
        return p;
    };
    int*   counts    = (int*)alloc((size_t)N * 4);
    int*   offsets   = (int*)alloc((size_t)(N + 1) * 4);
    int*   cursor    = (int*)alloc((size_t)N * 4);
    float* dinv      = (float*)alloc((size_t)N * 4);
    int nb = (N + SCAN_B - 1) / SCAN_B;
    int*   blockSums = (int*)alloc((size_t)nb * 4);
    int*   bin_base  = (int*)alloc((size_t)(nbins + 1) * 4);
    int*   bin_cur   = (int*)alloc((size_t)nbins * 4);
    int*   ssrc      = (int*)alloc((size_t)E * 4);
    unsigned short* W1t = (unsigned short*)alloc((size_t)128 * 512 * 2);
    unsigned short* h1  = (unsigned short*)alloc((size_t)N * 128 * 2);
    unsigned short* a1  = (unsigned short*)alloc((size_t)N * 128 * 2);
    float* h2        = (float*)alloc((size_t)N * 40 * 4);
    unsigned int* bpairs = (unsigned int*)h1;  // alias: E*4=6.4MB < 25.6MB, consumed pre-gemm1
    (void)ws_size; (void)n_in; (void)out_size;

    hipMemsetAsync(counts, 0, (size_t)N * 4, stream);
    count_deg_kernel<<<(E + 255) / 256, 256, 0, stream>>>(dst, E, counts);
    scan1_kernel<<<nb, SCAN_B, 0, stream>>>(counts, N, offsets, blockSums);
    scan2_kernel<<<1, 256, 0, stream>>>(blockSums, nb);
    scan3_kernel<<<nb, SCAN_B, 0, stream>>>(counts, offsets, blockSums, N, E, cursor, dinv);
    binbase_kernel<<<(nbins + 256) / 256, 256, 0, stream>>>(offsets, bin_base, bin_cur, nbins, N);
    binpass_kernel<<<(E + CHUNK - 1) / CHUNK, 256, 0, stream>>>(src, dst, E, bin_cur, bpairs, nbins);
    binscatter_kernel<<<nbins, 256, 0, stream>>>(bpairs, bin_base, cursor, ssrc);
    w1cast_kernel<<<256, 256, 0, stream>>>(W1, W1t);
    gemm1_mfma_kernel<<<(N + BM - 1) / BM, 256, 0, stream>>>(x, W1t, h1, N);
    agg1_kernel<<<(N + 15) / 16, 256, 0, stream>>>(h1, offsets, ssrc, dinv, b1, a1, N);
    gemm2_kernel<<<(N + 63) / 64, 256, 0, stream>>>(a1, W2, h2, N);
    agg2_kernel<<<(N + 3) / 4, 256, 0, stream>>>(h2, offsets, ssrc, dinv, b2, out, N);
}